// Round 7
// baseline (182.623 us; speedup 1.0000x reference)
//
#include <hip/hip_runtime.h>
#include <math.h>

#define N_TOT 8192
#define D 128
#define JSPLIT 8
#define NBLK 512            // (N_TOT/128) * JSPLIT

typedef unsigned short ushortT;
typedef __attribute__((ext_vector_type(8))) short short8;
typedef __attribute__((ext_vector_type(4))) float f32x4;

// ---------------- bf16 pack (RNE) ----------------
__device__ __forceinline__ unsigned f2bf(float f) {
    unsigned u = __float_as_uint(f);
    return (u + 0x7FFF + ((u >> 16) & 1)) >> 16;
}

// ---------------- prep: normalize->bf16, self-sim, pos pack ----------------
// Quarter-wave (16 lanes) per row. selfS[i] = sum_k bf16(hn_ik)^2 — the exact value the
// MFMA adds for the (i,i) pair (up to fp32 reassociation ~1ulp), subtracted in finalize.
__global__ __launch_bounds__(256) void prep_kernel(const float* __restrict__ h,
                                                   const float* __restrict__ pos,
                                                   unsigned* __restrict__ hn2,
                                                   float4* __restrict__ p4,
                                                   float* __restrict__ selfS) {
    const int tid = threadIdx.x;
    const int wave = tid >> 6, lane = tid & 63;
    const int quad = lane >> 4, l15 = lane & 15;
    const int row = blockIdx.x * 16 + wave * 4 + quad;

    const float4* g = reinterpret_cast<const float4*>(h + (size_t)row * D) + l15 * 2;
    float4 a = g[0], b = g[1];
    float ss = a.x * a.x + a.y * a.y + a.z * a.z + a.w * a.w
             + b.x * b.x + b.y * b.y + b.z * b.z + b.w * b.w;
#pragma unroll
    for (int m = 1; m < 16; m <<= 1) ss += __shfl_xor(ss, m, 64);
    float sc = 1.0f / fmaxf(sqrtf(ss), 1e-12f);

    float vals[8] = {a.x, a.y, a.z, a.w, b.x, b.y, b.z, b.w};
    unsigned u[8];
    float q = 0.f;
#pragma unroll
    for (int k = 0; k < 8; ++k) {
        u[k] = f2bf(vals[k] * sc);
        float bv = __uint_as_float(u[k] << 16);
        q = fmaf(bv, bv, q);
    }
    uint4 o;
    o.x = u[0] | (u[1] << 16);
    o.y = u[2] | (u[3] << 16);
    o.z = u[4] | (u[5] << 16);
    o.w = u[6] | (u[7] << 16);
    reinterpret_cast<uint4*>(hn2 + (size_t)row * 64)[l15] = o;

#pragma unroll
    for (int m = 1; m < 16; m <<= 1) q += __shfl_xor(q, m, 64);
    if (l15 == 0) selfS[row] = q;

    if (tid < 16) {
        int t = blockIdx.x * 16 + tid;
        float x = pos[3 * t], y = pos[3 * t + 1], z = pos[3 * t + 2];
        p4[t] = make_float4(x, y, z, x * x + y * y + z * z);
    }
}

// ---------------- XOR-swizzled staging via global_load_lds (width=16) ----------------
__device__ __forceinline__ void stage128(const ushortT* __restrict__ src, ushortT* dst,
                                         int wave, int lane) {
#pragma unroll
    for (int it = 0; it < 8; ++it) {
        int c = it * 4 + wave;                       // 1 KB chunk (4 rows)
        int rho = c * 4 + (lane >> 4);
        int k = (lane & 15) ^ (rho & 7);
        const ushortT* g = src + (size_t)rho * D + k * 8;
        __builtin_amdgcn_global_load_lds(
            (const __attribute__((address_space(1))) unsigned int*)g,
            (__attribute__((address_space(3))) unsigned int*)(dst + c * 512),
            16, 0, 0);
    }
}
__device__ __forceinline__ int swz(int r, int k) {
    return r * D + ((k ^ (r & 7)) * 8);
}

// ---------------- epilogue for one 16-column strip (no self handling!) ----------------
__device__ __forceinline__ void epi(const f32x4* a2, float4 pj,
                                    const float* pix, const float* piy, const float* piz,
                                    const float* qiw, float* Ea, float* Sa, int* Ci) {
    float thr = 0.5f * pj.w - 0.125f;
#pragma unroll
    for (int r = 0; r < 2; ++r)
#pragma unroll
        for (int v = 0; v < 4; ++v) {
            int idx = r * 4 + v;
            float s = a2[r][v];
            Ea[idx] += __expf(fmaf(s, 10.f, -10.f));
            float dot = fmaf(pix[idx], pj.x, fmaf(piy[idx], pj.y, piz[idx] * pj.z));
            bool isp = dot > thr + qiw[idx];
            Sa[idx] += isp ? s : 0.f;
            Ci[idx] += isp ? 1 : 0;
        }
}

// ---------------- main: MFMA sim + partials; last block finalizes ----------------
__global__ __launch_bounds__(256, 1) void main_kernel(const ushortT* __restrict__ hn,
                                                      const float4* __restrict__ p4,
                                                      const float* __restrict__ selfS,
                                                      float* __restrict__ Ep,
                                                      float* __restrict__ Sp,
                                                      float* __restrict__ Cp,
                                                      unsigned* __restrict__ cnt,
                                                      float* __restrict__ out) {
    __shared__ ushortT Bs[2][128 * D];               // 2 x 32 KB ping-pong (64 KB total)
    const int tid = threadIdx.x;
    const int wave = tid >> 6, lane = tid & 63;
    const int quad = lane >> 4, l15 = lane & 15;
    const int iblock = blockIdx.x * 128;
    const int jstart = blockIdx.y * (N_TOT / JSPLIT);

    stage128(hn + (size_t)iblock * D, Bs[1], wave, lane);   // A-tile -> buf1 (temp)
    stage128(hn + (size_t)jstart * D, Bs[0], wave, lane);   // B-tile 0 -> buf0

    float pix[8], piy[8], piz[8], qiw[8];
#pragma unroll
    for (int idx = 0; idx < 8; ++idx) {
        int i = iblock + wave * 32 + (idx >> 2) * 16 + quad * 4 + (idx & 3);
        float4 p = p4[i];
        pix[idx] = p.x; piy[idx] = p.y; piz[idx] = p.z; qiw[idx] = 0.5f * p.w;
    }
    float Ea[8], Sa[8];
    int Ci[8];
#pragma unroll
    for (int idx = 0; idx < 8; ++idx) { Ea[idx] = 0.f; Sa[idx] = 0.f; Ci[idx] = 0; }

    __syncthreads();                                 // A + B0 staged

    short8 afr[4][2];                                // hoist A frags (32 VGPRs)
#pragma unroll
    for (int ks = 0; ks < 4; ++ks)
#pragma unroll
        for (int r = 0; r < 2; ++r) {
            int ra = wave * 32 + r * 16 + l15;
            afr[ks][r] = *reinterpret_cast<const short8*>(&Bs[1][swz(ra, ks * 4 + quad)]);
        }
    __syncthreads();                                 // buf1 released

    for (int jt = 0; jt < 8; ++jt) {
        const int jtbase = jstart + jt * 128;
        if (jt < 7)
            stage128(hn + (size_t)(jtbase + 128) * D, Bs[(jt + 1) & 1], wave, lane);
        const ushortT* B = Bs[jt & 1];

        short8 bb[2][4];
        float4 pjv[2];
        f32x4 acc[2][2];

        // strip 0: load + MFMA
#pragma unroll
        for (int ks = 0; ks < 4; ++ks)
            bb[0][ks] = *reinterpret_cast<const short8*>(&B[swz(l15, ks * 4 + quad)]);
        pjv[0] = p4[jtbase + l15];
        acc[0][0] = (f32x4){0.f, 0.f, 0.f, 0.f};
        acc[0][1] = (f32x4){0.f, 0.f, 0.f, 0.f};
#pragma unroll
        for (int ks = 0; ks < 4; ++ks) {
            acc[0][0] = __builtin_amdgcn_mfma_f32_16x16x32_bf16(afr[ks][0], bb[0][ks], acc[0][0], 0, 0, 0);
            acc[0][1] = __builtin_amdgcn_mfma_f32_16x16x32_bf16(afr[ks][1], bb[0][ks], acc[0][1], 0, 0, 0);
        }
        // pipelined strips: prefetch(c) -> epilogue(c-1) hides ds_read + p4 + MFMA latency
#pragma unroll
        for (int c = 1; c < 8; ++c) {
            const int cur = c & 1, prv = cur ^ 1;
#pragma unroll
            for (int ks = 0; ks < 4; ++ks)
                bb[cur][ks] = *reinterpret_cast<const short8*>(&B[swz(c * 16 + l15, ks * 4 + quad)]);
            pjv[cur] = p4[jtbase + c * 16 + l15];
            epi(acc[prv], pjv[prv], pix, piy, piz, qiw, Ea, Sa, Ci);
            acc[cur][0] = (f32x4){0.f, 0.f, 0.f, 0.f};
            acc[cur][1] = (f32x4){0.f, 0.f, 0.f, 0.f};
#pragma unroll
            for (int ks = 0; ks < 4; ++ks) {
                acc[cur][0] = __builtin_amdgcn_mfma_f32_16x16x32_bf16(afr[ks][0], bb[cur][ks], acc[cur][0], 0, 0, 0);
                acc[cur][1] = __builtin_amdgcn_mfma_f32_16x16x32_bf16(afr[ks][1], bb[cur][ks], acc[cur][1], 0, 0, 0);
            }
        }
        epi(acc[1], pjv[1], pix, piy, piz, qiw, Ea, Sa, Ci);

        __syncthreads();                             // drains next-tile staging; releases B
    }

    // reduce across the 16 lanes (l15) sharing each i-row; write per-split partials
#pragma unroll
    for (int idx = 0; idx < 8; ++idx) {
        float Cf = (float)Ci[idx];
#pragma unroll
        for (int m = 1; m < 16; m <<= 1) {
            Ea[idx] += __shfl_xor(Ea[idx], m, 64);
            Sa[idx] += __shfl_xor(Sa[idx], m, 64);
            Cf += __shfl_xor(Cf, m, 64);
        }
        if (l15 == 0) {
            int i = iblock + wave * 32 + (idx >> 2) * 16 + quad * 4 + (idx & 3);
            size_t o = (size_t)blockIdx.y * N_TOT + i;
            Ep[o] = Ea[idx]; Sp[o] = Sa[idx]; Cp[o] = Cf;
        }
    }

    // ---- last-block finalize (threadFenceReduction pattern; LDS reused for flag/partials) ----
    unsigned* lastFlag = reinterpret_cast<unsigned*>(&Bs[0][0]);
    float2* wsum = reinterpret_cast<float2*>(&Bs[0][8]);
    __threadfence();                                 // publish partials device-wide
    __syncthreads();
    if (tid == 0) {
        unsigned t = atomicAdd(cnt, 1u);             // device-scope
        *lastFlag = (t == NBLK - 1) ? 1u : 0u;
    }
    __syncthreads();
    if (*lastFlag) {
        __threadfence();                             // acquire others' partials
        float sumL = 0.f, sumV = 0.f;
        for (int a = tid; a < N_TOT; a += 256) {
            float E = 0.f, S = 0.f, C = 0.f;
#pragma unroll
            for (int s = 0; s < JSPLIT; ++s) {
                E += Ep[(size_t)s * N_TOT + a];
                S += Sp[(size_t)s * N_TOT + a];
                C += Cp[(size_t)s * N_TOT + a];
            }
            float s0 = selfS[a];                     // remove the self pair
            E -= __expf(fmaf(s0, 10.f, -10.f));
            S -= s0;
            C -= 1.f;
            if (C > 0.5f) {
                float lse = 10.0f + logf(fmaxf(E, 1e-30f));
                sumL += -(10.0f * S - C * lse) / C;  // S stored in sim units
                sumV += 1.0f;
            }
        }
#pragma unroll
        for (int m = 1; m < 64; m <<= 1) {
            sumL += __shfl_xor(sumL, m, 64);
            sumV += __shfl_xor(sumV, m, 64);
        }
        if (lane == 0) wsum[wave] = make_float2(sumL, sumV);
        __syncthreads();
        if (tid == 0) {
            float L = wsum[0].x + wsum[1].x + wsum[2].x + wsum[3].x;
            float V = wsum[0].y + wsum[1].y + wsum[2].y + wsum[3].y;
            out[0] = L / fmaxf(V, 1.0f);
        }
    }
}

extern "C" void kernel_launch(void* const* d_in, const int* in_sizes, int n_in,
                              void* d_out, int out_size, void* d_ws, size_t ws_size,
                              hipStream_t stream) {
    const float* h = (const float*)d_in[0];     // [8,1024,128] fp32
    const float* pos = (const float*)d_in[1];   // [8,1024,3] fp32
    float* out = (float*)d_out;                 // scalar fp32

    char* ws = (char*)d_ws;
    ushortT* hn = (ushortT*)ws;                                   // 2 MB bf16
    float4* p4 = (float4*)(ws + (size_t)N_TOT * D * 2);           // 128 KB
    char* p = ws + (size_t)N_TOT * D * 2 + (size_t)N_TOT * 16;
    float* selfS = (float*)p; p += (size_t)N_TOT * 4;             // 32 KB
    float* Ep = (float*)p; p += (size_t)JSPLIT * N_TOT * 4;       // 256 KB
    float* Sp = (float*)p; p += (size_t)JSPLIT * N_TOT * 4;       // 256 KB
    float* Cp = (float*)p; p += (size_t)JSPLIT * N_TOT * 4;       // 256 KB
    unsigned* cnt = (unsigned*)p;                                 // 4 B

    hipMemsetAsync(cnt, 0, sizeof(unsigned), stream);             // ws is poisoned each call
    prep_kernel<<<N_TOT / 16, 256, 0, stream>>>(h, pos, (unsigned*)hn, p4, selfS);
    main_kernel<<<dim3(N_TOT / 128, JSPLIT), 256, 0, stream>>>(hn, p4, selfS,
                                                               Ep, Sp, Cp, cnt, out);
}